// Round 3
// baseline (245.359 us; speedup 1.0000x reference)
//
#include <hip/hip_runtime.h>

#define S_TOTAL 17064
#define NB 16
#define NC 80
// active blocks: per (b): ceil(3200/64)+ceil(800/64)+ceil(200/64)+ceil(52/64)+ceil(14/64)
//              = 50+13+4+1+1 = 69;  x16 batches = 1104
#define TOTAL_ACTIVE_BLOCKS 1104

typedef float vfloat4 __attribute__((ext_vector_type(4)));

struct Ptrs {
    const float* cls[5];
    const float* cnt[5];
    const float* reg[5];
    const float* cnt_t;   // [B,S,1]
    const float* reg_t;   // [B,S,4]
    const int*   cls_t;   // [B,S,1]
    float*       ws;      // [0:16) cls, [16:32) cnt, [32:48) reg, [48:64) pos, [64] counter
    float*       out;
};

__device__ __forceinline__ float focal_term(float x, bool o) {
    const float xs = o ? x : -x;            // p_t = sigmoid(xs)
    const float af = o ? 0.25f : 0.75f;
    const float em = __expf(-xs);
    const float pt = 1.0f / (1.0f + em);
    const float q  = em * pt;               // 1 - p_t
    return af * q * q * __logf(1.0f + em);  // -af*(1-pt)^2*log(pt)
}

__device__ __forceinline__ float giou_term(float pl, float pt_, float pr, float pb,
                                           float tl, float tt, float tr, float tb) {
    const float overlap = fmaxf(fminf(pr, tr) + fminf(pl, tl), 0.0f) *
                          fmaxf(fminf(pb, tb) + fminf(pt_, tt), 0.0f);
    const float area1 = (pr + pl) * (pb + pt_);
    const float area2 = (tr + tl) * (tb + tt);
    const float uni = area1 + area2 - overlap;
    const float iou = overlap / uni;
    const float ga = fmaxf(fmaxf(pr, tr) + fmaxf(pl, tl), 0.0f) *
                     fmaxf(fmaxf(pb, tb) + fmaxf(pt_, tt), 0.0f);
    const float giou = iou - (ga - uni) / fmaxf(ga, 1e-10f);
    return 1.0f - giou;
}

__device__ __forceinline__ float bce_term(float x, float t) {
    return fmaxf(x, 0.0f) - x * t + __logf(1.0f + __expf(-fabsf(x)));
}

__global__ __launch_bounds__(512) void fcos_main(Ptrs p) {
    constexpr int HW[5]  = {12800, 3200, 800, 208, 56};
    constexpr int OFF[5] = {0, 12800, 16000, 16800, 17008};

    const int lvl = blockIdx.z;
    const int b   = blockIdx.y;
    const int hw  = HW[lvl];
    const int off = OFF[lvl];
    const int nq  = hw >> 2;                      // location quads this level

    if ((int)(blockIdx.x * 64) >= nq) return;     // dead block (small levels)

    const int g    = threadIdx.x >> 6;            // wave id: class group 0..7
    const int lane = threadIdx.x & 63;
    const int quad = blockIdx.x * 64 + lane;
    const bool active = (quad < nq);
    const int s0  = quad << 2;
    const int gs0 = b * S_TOTAL + off + s0;       // global loc index of elem 0

    float a0 = 0.f, a1 = 0.f, a2 = 0.f, a3 = 0.f;           // focal, 4 chains
    float cnt_acc = 0.f, reg_acc = 0.f, pos_acc = 0.f;      // wave 0 only

    if (active) {
        const int4 tq = *(const int4*)(p.cls_t + gs0);      // targets, 4 locs
        const float* cp = p.cls[lvl] + (size_t)(b * NC) * hw + s0;
        const int c0 = g * 10;
        #pragma unroll 2
        for (int cc = 0; cc < 10; ++cc) {
            const int c = c0 + cc;
            const vfloat4 v = __builtin_nontemporal_load(
                (const vfloat4*)(cp + (size_t)c * hw));
            a0 += focal_term(v.x, tq.x == c + 1);
            a1 += focal_term(v.y, tq.y == c + 1);
            a2 += focal_term(v.z, tq.z == c + 1);
            a3 += focal_term(v.w, tq.w == c + 1);
        }

        if (g == 0) {
            // ---- centerness + mask ----
            const float4 xc = *(const float4*)(p.cnt[lvl] + (size_t)b * hw + s0);
            const float4 tC = *(const float4*)(p.cnt_t + gs0);
            const float m0 = (tC.x > -1.0f) ? 1.0f : 0.0f;
            const float m1 = (tC.y > -1.0f) ? 1.0f : 0.0f;
            const float m2 = (tC.z > -1.0f) ? 1.0f : 0.0f;
            const float m3 = (tC.w > -1.0f) ? 1.0f : 0.0f;
            pos_acc = m0 + m1 + m2 + m3;
            cnt_acc = bce_term(xc.x, tC.x) * m0 + bce_term(xc.y, tC.y) * m1 +
                      bce_term(xc.z, tC.z) * m2 + bce_term(xc.w, tC.w) * m3;

            // ---- GIoU ----
            const float* rp = p.reg[lvl] + (size_t)(b * 4) * hw + s0;
            const float4 pl = *(const float4*)(rp);
            const float4 pt_ = *(const float4*)(rp + (size_t)hw);
            const float4 pr = *(const float4*)(rp + 2 * (size_t)hw);
            const float4 pb = *(const float4*)(rp + 3 * (size_t)hw);
            const float4 t0 = *(const float4*)(p.reg_t + (size_t)(gs0 + 0) * 4);
            const float4 t1 = *(const float4*)(p.reg_t + (size_t)(gs0 + 1) * 4);
            const float4 t2 = *(const float4*)(p.reg_t + (size_t)(gs0 + 2) * 4);
            const float4 t3 = *(const float4*)(p.reg_t + (size_t)(gs0 + 3) * 4);
            reg_acc = giou_term(pl.x, pt_.x, pr.x, pb.x, t0.x, t0.y, t0.z, t0.w) * m0 +
                      giou_term(pl.y, pt_.y, pr.y, pb.y, t1.x, t1.y, t1.z, t1.w) * m1 +
                      giou_term(pl.z, pt_.z, pr.z, pb.z, t2.x, t2.y, t2.z, t2.w) * m2 +
                      giou_term(pl.w, pt_.w, pr.w, pb.w, t3.x, t3.y, t3.z, t3.w) * m3;
        }
    }

    // ---- reduction: wave shuffle, then LDS across 8 waves (cls only) ----
    float cls_acc = (a0 + a1) + (a2 + a3);
    #pragma unroll
    for (int d = 32; d; d >>= 1) {
        cls_acc += __shfl_down(cls_acc, d);
        cnt_acc += __shfl_down(cnt_acc, d);
        reg_acc += __shfl_down(reg_acc, d);
        pos_acc += __shfl_down(pos_acc, d);
    }

    __shared__ float cls_red[8];
    if (lane == 0) cls_red[g] = cls_acc;
    __syncthreads();
    if (threadIdx.x == 0) {
        float c0 = 0.f;
        #pragma unroll
        for (int w = 0; w < 8; ++w) c0 += cls_red[w];
        atomicAdd(&p.ws[b],      c0);
        atomicAdd(&p.ws[16 + b], cnt_acc);   // thread 0 holds wave-0 totals
        atomicAdd(&p.ws[32 + b], reg_acc);
        atomicAdd(&p.ws[48 + b], pos_acc);
    }

    // ---- last-block finalize ----
    __shared__ int is_last;
    if (threadIdx.x == 0) {
        __threadfence();
        const int old = __hip_atomic_fetch_add((int*)(p.ws + 64), 1,
                            __ATOMIC_ACQ_REL, __HIP_MEMORY_SCOPE_AGENT);
        is_last = (old == TOTAL_ACTIVE_BLOCKS - 1) ? 1 : 0;
    }
    __syncthreads();
    if (is_last && threadIdx.x < 64) {
        __threadfence();
        const int t = threadIdx.x;
        float l0 = 0.f, l1 = 0.f, l2 = 0.f;
        if (t < NB) {
            const float np = fmaxf(__hip_atomic_load(&p.ws[48 + t],
                __ATOMIC_RELAXED, __HIP_MEMORY_SCOPE_AGENT), 1.0f);
            l0 = __hip_atomic_load(&p.ws[t],
                __ATOMIC_RELAXED, __HIP_MEMORY_SCOPE_AGENT) / np;
            l1 = __hip_atomic_load(&p.ws[16 + t],
                __ATOMIC_RELAXED, __HIP_MEMORY_SCOPE_AGENT) / np;
            l2 = __hip_atomic_load(&p.ws[32 + t],
                __ATOMIC_RELAXED, __HIP_MEMORY_SCOPE_AGENT) / np;
        }
        #pragma unroll
        for (int d = 32; d; d >>= 1) {
            l0 += __shfl_down(l0, d);
            l1 += __shfl_down(l1, d);
            l2 += __shfl_down(l2, d);
        }
        if (t == 0) {
            l0 *= (1.0f / NB);
            l1 *= (1.0f / NB);
            l2 *= (1.0f / NB);
            p.out[0] = l0;
            p.out[1] = l1;
            p.out[2] = l2;
            p.out[3] = l0 + l1 + l2;
        }
    }
}

extern "C" void kernel_launch(void* const* d_in, const int* in_sizes, int n_in,
                              void* d_out, int out_size, void* d_ws, size_t ws_size,
                              hipStream_t stream) {
    Ptrs p;
    for (int i = 0; i < 5; ++i) {
        p.cls[i] = (const float*)d_in[3 * i + 0];
        p.cnt[i] = (const float*)d_in[3 * i + 1];
        p.reg[i] = (const float*)d_in[3 * i + 2];
    }
    p.cnt_t = (const float*)d_in[15];
    p.reg_t = (const float*)d_in[16];
    p.cls_t = (const int*)  d_in[17];
    p.ws    = (float*)d_ws;
    p.out   = (float*)d_out;

    (void)hipMemsetAsync(d_ws, 0, 68 * sizeof(float), stream);  // sums + counter

    dim3 grid(50, NB, 5);
    fcos_main<<<grid, 512, 0, stream>>>(p);
}

// Round 4
// 224.617 us; speedup vs baseline: 1.0923x; 1.0923x over previous
//
#include <hip/hip_runtime.h>

#define S_TOTAL 17064
#define NB 16
#define NC 80
// active blocks: per (b): 50+13+4+1+1 = 69;  x16 batches = 1104
#define TOTAL_ACTIVE_BLOCKS 1104

typedef float vfloat4 __attribute__((ext_vector_type(4)));

struct Ptrs {
    const float* cls[5];
    const float* cnt[5];
    const float* reg[5];
    const float* cnt_t;   // [B,S,1]
    const float* reg_t;   // [B,S,4]
    const int*   cls_t;   // [B,S,1]
    float*       ws;      // [0:16) cls, [16:32) cnt, [32:48) reg, [48:64) pos, [64] counter
    float*       out;
};

__device__ __forceinline__ float focal_term(float x, bool o) {
    const float xs = o ? x : -x;            // p_t = sigmoid(xs)
    const float af = o ? 0.25f : 0.75f;
    const float em = __expf(-xs);
    const float pt = 1.0f / (1.0f + em);
    const float q  = em * pt;               // 1 - p_t
    return af * q * q * __logf(1.0f + em);  // -af*(1-pt)^2*log(pt)
}

__device__ __forceinline__ float giou_term(float pl, float pt_, float pr, float pb,
                                           float tl, float tt, float tr, float tb) {
    const float overlap = fmaxf(fminf(pr, tr) + fminf(pl, tl), 0.0f) *
                          fmaxf(fminf(pb, tb) + fminf(pt_, tt), 0.0f);
    const float area1 = (pr + pl) * (pb + pt_);
    const float area2 = (tr + tl) * (tb + tt);
    const float uni = area1 + area2 - overlap;
    const float iou = overlap / uni;
    const float ga = fmaxf(fmaxf(pr, tr) + fmaxf(pl, tl), 0.0f) *
                     fmaxf(fmaxf(pb, tb) + fmaxf(pt_, tt), 0.0f);
    const float giou = iou - (ga - uni) / fmaxf(ga, 1e-10f);
    return 1.0f - giou;
}

__device__ __forceinline__ float bce_term(float x, float t) {
    return fmaxf(x, 0.0f) - x * t + __logf(1.0f + __expf(-fabsf(x)));
}

__global__ __launch_bounds__(512) void fcos_main(Ptrs p) {
    constexpr int HW[5]  = {12800, 3200, 800, 208, 56};
    constexpr int OFF[5] = {0, 12800, 16000, 16800, 17008};

    const int lvl = blockIdx.z;
    const int b   = blockIdx.y;
    const int hw  = HW[lvl];
    const int off = OFF[lvl];
    const int nq  = hw >> 2;                      // location quads this level

    if ((int)(blockIdx.x * 64) >= nq) return;     // dead block (small levels)

    const int g    = threadIdx.x >> 6;            // wave id: class group 0..7
    const int lane = threadIdx.x & 63;
    const int quad = blockIdx.x * 64 + lane;
    const bool active = (quad < nq);
    const int s0  = quad << 2;
    const int gs0 = b * S_TOTAL + off + s0;       // global loc index of elem 0

    float a0 = 0.f, a1 = 0.f, a2 = 0.f, a3 = 0.f;           // focal, 4 chains
    float cnt_acc = 0.f, reg_acc = 0.f, pos_acc = 0.f;      // wave 0 only

    if (active) {
        // ---- issue ALL loads first: max memory-level parallelism ----
        const int4 tq = *(const int4*)(p.cls_t + gs0);      // targets, 4 locs
        const float* cp = p.cls[lvl] + (size_t)(b * NC) * hw + s0;
        const int c0 = g * 10;
        vfloat4 v[10];
        #pragma unroll
        for (int cc = 0; cc < 10; ++cc)
            v[cc] = *(const vfloat4*)(cp + (size_t)(c0 + cc) * hw);

        float4 xc, tC, pl, pt_, pr, pb, t0, t1, t2, t3;
        if (g == 0) {
            xc  = *(const float4*)(p.cnt[lvl] + (size_t)b * hw + s0);
            tC  = *(const float4*)(p.cnt_t + gs0);
            const float* rp = p.reg[lvl] + (size_t)(b * 4) * hw + s0;
            pl  = *(const float4*)(rp);
            pt_ = *(const float4*)(rp + (size_t)hw);
            pr  = *(const float4*)(rp + 2 * (size_t)hw);
            pb  = *(const float4*)(rp + 3 * (size_t)hw);
            t0  = *(const float4*)(p.reg_t + (size_t)(gs0 + 0) * 4);
            t1  = *(const float4*)(p.reg_t + (size_t)(gs0 + 1) * 4);
            t2  = *(const float4*)(p.reg_t + (size_t)(gs0 + 2) * 4);
            t3  = *(const float4*)(p.reg_t + (size_t)(gs0 + 3) * 4);
        }

        // ---- focal over this wave's 10 classes ----
        #pragma unroll
        for (int cc = 0; cc < 10; ++cc) {
            const int c = c0 + cc;
            a0 += focal_term(v[cc].x, tq.x == c + 1);
            a1 += focal_term(v[cc].y, tq.y == c + 1);
            a2 += focal_term(v[cc].z, tq.z == c + 1);
            a3 += focal_term(v[cc].w, tq.w == c + 1);
        }

        if (g == 0) {
            const float m0 = (tC.x > -1.0f) ? 1.0f : 0.0f;
            const float m1 = (tC.y > -1.0f) ? 1.0f : 0.0f;
            const float m2 = (tC.z > -1.0f) ? 1.0f : 0.0f;
            const float m3 = (tC.w > -1.0f) ? 1.0f : 0.0f;
            pos_acc = m0 + m1 + m2 + m3;
            cnt_acc = bce_term(xc.x, tC.x) * m0 + bce_term(xc.y, tC.y) * m1 +
                      bce_term(xc.z, tC.z) * m2 + bce_term(xc.w, tC.w) * m3;
            reg_acc = giou_term(pl.x, pt_.x, pr.x, pb.x, t0.x, t0.y, t0.z, t0.w) * m0 +
                      giou_term(pl.y, pt_.y, pr.y, pb.y, t1.x, t1.y, t1.z, t1.w) * m1 +
                      giou_term(pl.z, pt_.z, pr.z, pb.z, t2.x, t2.y, t2.z, t2.w) * m2 +
                      giou_term(pl.w, pt_.w, pr.w, pb.w, t3.x, t3.y, t3.z, t3.w) * m3;
        }
    }

    // ---- reduction: wave shuffle, then LDS across 8 waves (cls only) ----
    float cls_acc = (a0 + a1) + (a2 + a3);
    #pragma unroll
    for (int d = 32; d; d >>= 1) {
        cls_acc += __shfl_down(cls_acc, d);
        cnt_acc += __shfl_down(cnt_acc, d);
        reg_acc += __shfl_down(reg_acc, d);
        pos_acc += __shfl_down(pos_acc, d);
    }

    __shared__ float cls_red[8];
    if (lane == 0) cls_red[g] = cls_acc;
    __syncthreads();
    if (threadIdx.x == 0) {
        float c0s = 0.f;
        #pragma unroll
        for (int w = 0; w < 8; ++w) c0s += cls_red[w];
        atomicAdd(&p.ws[b],      c0s);
        atomicAdd(&p.ws[16 + b], cnt_acc);   // thread 0 holds wave-0 totals
        atomicAdd(&p.ws[32 + b], reg_acc);
        atomicAdd(&p.ws[48 + b], pos_acc);
    }

    // ---- last-block finalize ----
    __shared__ int is_last;
    if (threadIdx.x == 0) {
        __threadfence();
        const int old = __hip_atomic_fetch_add((int*)(p.ws + 64), 1,
                            __ATOMIC_ACQ_REL, __HIP_MEMORY_SCOPE_AGENT);
        is_last = (old == TOTAL_ACTIVE_BLOCKS - 1) ? 1 : 0;
    }
    __syncthreads();
    if (is_last && threadIdx.x < 64) {
        __threadfence();
        const int t = threadIdx.x;
        float l0 = 0.f, l1 = 0.f, l2 = 0.f;
        if (t < NB) {
            const float np = fmaxf(__hip_atomic_load(&p.ws[48 + t],
                __ATOMIC_RELAXED, __HIP_MEMORY_SCOPE_AGENT), 1.0f);
            l0 = __hip_atomic_load(&p.ws[t],
                __ATOMIC_RELAXED, __HIP_MEMORY_SCOPE_AGENT) / np;
            l1 = __hip_atomic_load(&p.ws[16 + t],
                __ATOMIC_RELAXED, __HIP_MEMORY_SCOPE_AGENT) / np;
            l2 = __hip_atomic_load(&p.ws[32 + t],
                __ATOMIC_RELAXED, __HIP_MEMORY_SCOPE_AGENT) / np;
        }
        #pragma unroll
        for (int d = 32; d; d >>= 1) {
            l0 += __shfl_down(l0, d);
            l1 += __shfl_down(l1, d);
            l2 += __shfl_down(l2, d);
        }
        if (t == 0) {
            l0 *= (1.0f / NB);
            l1 *= (1.0f / NB);
            l2 *= (1.0f / NB);
            p.out[0] = l0;
            p.out[1] = l1;
            p.out[2] = l2;
            p.out[3] = l0 + l1 + l2;
        }
    }
}

extern "C" void kernel_launch(void* const* d_in, const int* in_sizes, int n_in,
                              void* d_out, int out_size, void* d_ws, size_t ws_size,
                              hipStream_t stream) {
    Ptrs p;
    for (int i = 0; i < 5; ++i) {
        p.cls[i] = (const float*)d_in[3 * i + 0];
        p.cnt[i] = (const float*)d_in[3 * i + 1];
        p.reg[i] = (const float*)d_in[3 * i + 2];
    }
    p.cnt_t = (const float*)d_in[15];
    p.reg_t = (const float*)d_in[16];
    p.cls_t = (const int*)  d_in[17];
    p.ws    = (float*)d_ws;
    p.out   = (float*)d_out;

    (void)hipMemsetAsync(d_ws, 0, 68 * sizeof(float), stream);  // sums + counter

    dim3 grid(50, NB, 5);
    fcos_main<<<grid, 512, 0, stream>>>(p);
}

// Round 5
// 187.240 us; speedup vs baseline: 1.3104x; 1.1996x over previous
//
#include <hip/hip_runtime.h>

#define S_TOTAL 17064
#define NB 16
#define NC 80
#define QPB 4266              // location-quads per batch image (sum hw/4)
#define NXQ 17                // quad-chunks of 256 per (b,half): 17*256=4352 >= 4266
#define TOTAL_BLOCKS (NXQ * 2 * NB)   // 544, all do work

typedef float vfloat4 __attribute__((ext_vector_type(4)));

struct Ptrs {
    const float* cls[5];
    const float* cnt[5];
    const float* reg[5];
    const float* cnt_t;   // [B,S,1]
    const float* reg_t;   // [B,S,4]
    const int*   cls_t;   // [B,S,1]
    float*       ws;      // [0:16) cls, [16:32) cnt, [32:48) reg, [48:64) pos, [64] counter
    float*       out;
};

__device__ __forceinline__ float focal_term(float x, bool o) {
    const float xs = o ? x : -x;            // p_t = sigmoid(xs)
    const float af = o ? 0.25f : 0.75f;
    const float em = __expf(-xs);
    const float pt = 1.0f / (1.0f + em);
    const float q  = em * pt;               // 1 - p_t
    return af * q * q * __logf(1.0f + em);  // -af*(1-pt)^2*log(pt)
}

__device__ __forceinline__ float giou_term(float pl, float pt_, float pr, float pb,
                                           float tl, float tt, float tr, float tb) {
    const float overlap = fmaxf(fminf(pr, tr) + fminf(pl, tl), 0.0f) *
                          fmaxf(fminf(pb, tb) + fminf(pt_, tt), 0.0f);
    const float area1 = (pr + pl) * (pb + pt_);
    const float area2 = (tr + tl) * (tb + tt);
    const float uni = area1 + area2 - overlap;
    const float iou = overlap / uni;
    const float ga = fmaxf(fmaxf(pr, tr) + fmaxf(pl, tl), 0.0f) *
                     fmaxf(fmaxf(pb, tb) + fmaxf(pt_, tt), 0.0f);
    const float giou = iou - (ga - uni) / fmaxf(ga, 1e-10f);
    return 1.0f - giou;
}

__device__ __forceinline__ float bce_term(float x, float t) {
    return fmaxf(x, 0.0f) - x * t + __logf(1.0f + __expf(-fabsf(x)));
}

__global__ __launch_bounds__(256) void fcos_main(Ptrs p) {
    const int bx = blockIdx.x;              // 0..33
    const int b  = blockIdx.y;              // 0..15
    const int h  = (bx >= NXQ) ? 1 : 0;     // class half
    const int xq = h ? bx - NXQ : bx;
    const int fq = xq * 256 + threadIdx.x;  // flat quad id within image
    const int c0 = h * 40;                  // first class of this half

    // flat quad -> (level, s0)
    int lvl, qb, hw, off;
    if (fq < 3200)      { lvl = 0; qb = 0;    hw = 12800; off = 0;     }
    else if (fq < 4000) { lvl = 1; qb = 3200; hw = 3200;  off = 12800; }
    else if (fq < 4200) { lvl = 2; qb = 4000; hw = 800;   off = 16000; }
    else if (fq < 4252) { lvl = 3; qb = 4200; hw = 208;   off = 16800; }
    else                { lvl = 4; qb = 4252; hw = 56;    off = 17008; }
    const bool active = (fq < QPB);

    float a0 = 0.f, a1 = 0.f, a2 = 0.f, a3 = 0.f;
    float cnt_acc = 0.f, reg_acc = 0.f, pos_acc = 0.f;

    if (active) {
        const int s0  = (fq - qb) << 2;
        const int gs0 = b * S_TOTAL + off + s0;
        const int4 tq = *(const int4*)(p.cls_t + gs0);
        const float* cp = p.cls[lvl] + (size_t)((b * NC + c0) * hw + s0);

        // ---- 40-class focal loop, 8-deep register pipeline ----
        vfloat4 buf[8];
        #pragma unroll
        for (int j = 0; j < 8; ++j)
            buf[j] = *(const vfloat4*)(cp + (size_t)(j * hw));

        #pragma unroll
        for (int blk = 0; blk < 5; ++blk) {
            vfloat4 nxt[8];
            if (blk < 4) {
                #pragma unroll
                for (int j = 0; j < 8; ++j)
                    nxt[j] = *(const vfloat4*)(cp + (size_t)((blk * 8 + 8 + j) * hw));
            }
            #pragma unroll
            for (int j = 0; j < 8; ++j) {
                const int c = c0 + blk * 8 + j;
                a0 += focal_term(buf[j].x, tq.x == c + 1);
                a1 += focal_term(buf[j].y, tq.y == c + 1);
                a2 += focal_term(buf[j].z, tq.z == c + 1);
                a3 += focal_term(buf[j].w, tq.w == c + 1);
            }
            if (blk < 4) {
                #pragma unroll
                for (int j = 0; j < 8; ++j) buf[j] = nxt[j];
            }
        }

        // ---- cnt + GIoU, half-0 blocks only (after loop: regs free) ----
        if (h == 0) {
            const float4 xc  = *(const float4*)(p.cnt[lvl] + (size_t)(b * hw + s0));
            const float4 tC  = *(const float4*)(p.cnt_t + gs0);
            const float* rp  = p.reg[lvl] + (size_t)(b * 4 * hw + s0);
            const float4 pl  = *(const float4*)(rp);
            const float4 pt_ = *(const float4*)(rp + (size_t)hw);
            const float4 pr  = *(const float4*)(rp + (size_t)(2 * hw));
            const float4 pb  = *(const float4*)(rp + (size_t)(3 * hw));
            const float4 t0  = *(const float4*)(p.reg_t + (size_t)(gs0 + 0) * 4);
            const float4 t1  = *(const float4*)(p.reg_t + (size_t)(gs0 + 1) * 4);
            const float4 t2  = *(const float4*)(p.reg_t + (size_t)(gs0 + 2) * 4);
            const float4 t3  = *(const float4*)(p.reg_t + (size_t)(gs0 + 3) * 4);

            const float m0 = (tC.x > -1.0f) ? 1.0f : 0.0f;
            const float m1 = (tC.y > -1.0f) ? 1.0f : 0.0f;
            const float m2 = (tC.z > -1.0f) ? 1.0f : 0.0f;
            const float m3 = (tC.w > -1.0f) ? 1.0f : 0.0f;
            pos_acc = m0 + m1 + m2 + m3;
            cnt_acc = bce_term(xc.x, tC.x) * m0 + bce_term(xc.y, tC.y) * m1 +
                      bce_term(xc.z, tC.z) * m2 + bce_term(xc.w, tC.w) * m3;
            reg_acc = giou_term(pl.x, pt_.x, pr.x, pb.x, t0.x, t0.y, t0.z, t0.w) * m0 +
                      giou_term(pl.y, pt_.y, pr.y, pb.y, t1.x, t1.y, t1.z, t1.w) * m1 +
                      giou_term(pl.z, pt_.z, pr.z, pb.z, t2.x, t2.y, t2.z, t2.w) * m2 +
                      giou_term(pl.w, pt_.w, pr.w, pb.w, t3.x, t3.y, t3.z, t3.w) * m3;
        }
    }

    // ---- block reduction ----
    float cls_acc = (a0 + a1) + (a2 + a3);
    #pragma unroll
    for (int d = 32; d; d >>= 1) {
        cls_acc += __shfl_down(cls_acc, d);
        cnt_acc += __shfl_down(cnt_acc, d);
        reg_acc += __shfl_down(reg_acc, d);
        pos_acc += __shfl_down(pos_acc, d);
    }

    __shared__ float red[4][4];
    const int wave = threadIdx.x >> 6;
    const int lane = threadIdx.x & 63;
    if (lane == 0) {
        red[0][wave] = cls_acc;
        red[1][wave] = cnt_acc;
        red[2][wave] = reg_acc;
        red[3][wave] = pos_acc;
    }
    __syncthreads();
    if (threadIdx.x == 0) {
        float c0s = red[0][0] + red[0][1] + red[0][2] + red[0][3];
        atomicAdd(&p.ws[b], c0s);
        if (h == 0) {
            atomicAdd(&p.ws[16 + b], red[1][0] + red[1][1] + red[1][2] + red[1][3]);
            atomicAdd(&p.ws[32 + b], red[2][0] + red[2][1] + red[2][2] + red[2][3]);
            atomicAdd(&p.ws[48 + b], red[3][0] + red[3][1] + red[3][2] + red[3][3]);
        }
    }

    // ---- last-block finalize ----
    __shared__ int is_last;
    if (threadIdx.x == 0) {
        __threadfence();
        const int old = __hip_atomic_fetch_add((int*)(p.ws + 64), 1,
                            __ATOMIC_ACQ_REL, __HIP_MEMORY_SCOPE_AGENT);
        is_last = (old == TOTAL_BLOCKS - 1) ? 1 : 0;
    }
    __syncthreads();
    if (is_last && threadIdx.x < 64) {
        __threadfence();
        const int t = threadIdx.x;
        float l0 = 0.f, l1 = 0.f, l2 = 0.f;
        if (t < NB) {
            const float np = fmaxf(__hip_atomic_load(&p.ws[48 + t],
                __ATOMIC_RELAXED, __HIP_MEMORY_SCOPE_AGENT), 1.0f);
            l0 = __hip_atomic_load(&p.ws[t],
                __ATOMIC_RELAXED, __HIP_MEMORY_SCOPE_AGENT) / np;
            l1 = __hip_atomic_load(&p.ws[16 + t],
                __ATOMIC_RELAXED, __HIP_MEMORY_SCOPE_AGENT) / np;
            l2 = __hip_atomic_load(&p.ws[32 + t],
                __ATOMIC_RELAXED, __HIP_MEMORY_SCOPE_AGENT) / np;
        }
        #pragma unroll
        for (int d = 32; d; d >>= 1) {
            l0 += __shfl_down(l0, d);
            l1 += __shfl_down(l1, d);
            l2 += __shfl_down(l2, d);
        }
        if (t == 0) {
            l0 *= (1.0f / NB);
            l1 *= (1.0f / NB);
            l2 *= (1.0f / NB);
            p.out[0] = l0;
            p.out[1] = l1;
            p.out[2] = l2;
            p.out[3] = l0 + l1 + l2;
        }
    }
}

extern "C" void kernel_launch(void* const* d_in, const int* in_sizes, int n_in,
                              void* d_out, int out_size, void* d_ws, size_t ws_size,
                              hipStream_t stream) {
    Ptrs p;
    for (int i = 0; i < 5; ++i) {
        p.cls[i] = (const float*)d_in[3 * i + 0];
        p.cnt[i] = (const float*)d_in[3 * i + 1];
        p.reg[i] = (const float*)d_in[3 * i + 2];
    }
    p.cnt_t = (const float*)d_in[15];
    p.reg_t = (const float*)d_in[16];
    p.cls_t = (const int*)  d_in[17];
    p.ws    = (float*)d_ws;
    p.out   = (float*)d_out;

    (void)hipMemsetAsync(d_ws, 0, 68 * sizeof(float), stream);  // sums + counter

    dim3 grid(2 * NXQ, NB, 1);   // 544 workgroups, all active
    fcos_main<<<grid, 256, 0, stream>>>(p);
}